// Round 18
// baseline (101.075 us; speedup 1.0000x reference)
//
#include <hip/hip_runtime.h>
#include <cmath>

#define NWP 128
#define NSEG 4
#define SEGLEN 32          // NWP / NSEG
#define PTS 64             // points per block
#define BLOCK 256          // PTS * NSEG = 4 waves

// r18: MEASUREMENT ROUND. Kernel byte-identical to r17 (passed, 69.4 us).
// Idempotent scan launched 4x: (bench_r18 - bench_r17)/3 = dispatch_overhead
// + warm_exec for THIS kernel. Discriminates:
//   overhead-dominated (~10-14 us/launch -> bench ~100-112): single-dispatch
//     residual is harness-fixed (fills 44 + dispatch ~10 + cold); roofline.
//   exec-dominated (~24-28 us/launch -> bench ~145-150): warm exec really is
//     ~26 us; bisect the loop body next.
__global__ __launch_bounds__(BLOCK) void magnet_scan_r18(
    const float* __restrict__ points,
    const float* __restrict__ centers,
    const float* __restrict__ raw_moment,
    const float* __restrict__ raw_dwell,
    float* __restrict__ out,
    int n_points)
{
    __shared__ float4 s_w0[NWP];        // {cx, cy, cz, dt}
    __shared__ float4 s_w1[NWP];        // {mx, my, mz, d_k}
    __shared__ float4 sh_a[NSEG][PTS];  // {ox, oy, oz, at}
    __shared__ float2 sh_b[NSEG][PTS];  // {peak2, fired}

    const int t = threadIdx.x;
    if (t < NWP) {
        const float cx = centers[3 * t + 0];
        const float cy = centers[3 * t + 1];
        const float cz = centers[3 * t + 2];
        // tanh(x) = 1 - 2/(exp2(2x/ln2)+1)
        const float L2E2 = 2.8853900817779268f;  // 2/ln2
        const float ex0 = __builtin_amdgcn_exp2f(raw_moment[3 * t + 0] * L2E2);
        const float ex1 = __builtin_amdgcn_exp2f(raw_moment[3 * t + 1] * L2E2);
        const float ex2 = __builtin_amdgcn_exp2f(raw_moment[3 * t + 2] * L2E2);
        const float mx = 0.05f * (1.0f - 2.0f * __builtin_amdgcn_rcpf(ex0 + 1.0f));
        const float my = 0.05f * (1.0f - 2.0f * __builtin_amdgcn_rcpf(ex1 + 1.0f));
        const float mz = 0.05f * (1.0f - 2.0f * __builtin_amdgcn_rcpf(ex2 + 1.0f));
        // sigmoid(x) = 1/(1+exp2(-x/ln2))
        const float ed = __builtin_amdgcn_exp2f(raw_dwell[t] * -1.4426950408889634f);
        const float dtv = 0.01f + 0.19f * __builtin_amdgcn_rcpf(1.0f + ed);
        // d_k = exp2(-(0.2/ln2)*(127-k))
        const float dk = __builtin_amdgcn_exp2f(
            -0.28853900817779268f * (float)(NWP - 1 - t));
        s_w0[t] = make_float4(cx, cy, cz, dtv);
        s_w1[t] = make_float4(mx, my, mz, dk);
    }
    __syncthreads();

    const int pt = t & (PTS - 1);
    const int seg = t >> 6;             // == wave id
    int p = blockIdx.x * PTS + pt;
    const bool valid = p < n_points;
    p = valid ? p : (n_points - 1);

    const float px = points[3 * p + 0];
    const float py = points[3 * p + 1];
    // pz == 0 by construction

    const int kbase = seg * SEGLEN;

    // segment seed: field at kbase-1; segment 0 seeds with o0 = (0,0,1).
    float gpx = 0.0f, gpy = 0.0f, gpz = 1.0f, b2p = 1.0f;
    if (seg != 0) {
        const float4 w0 = s_w0[kbase - 1];
        const float4 w1 = s_w1[kbase - 1];
        const float rx = px - w0.x, ry = py - w0.y;
        const float r2 = fmaf(rx, rx, fmaf(ry, ry, w0.z * w0.z));
        const float mdotr = fmaf(w1.z, -w0.z, fmaf(w1.y, ry, w1.x * rx));
        const float t3 = 3.0f * mdotr;
        gpx = fmaf(t3, rx, -(w1.x * r2));
        gpy = fmaf(t3, ry, -(w1.y * r2));
        gpz = fmaf(t3, -w0.z, -(w1.z * r2));
        b2p = fmaf(gpz, gpz, fmaf(gpy, gpy, gpx * gpx));
    }

    float gsx = 0.0f, gsy = 0.0f, gsz = 1.0f, b2s = 1.0f;  // last fired
    float at = 0.0f, peak2 = 0.0f, fired = 0.0f;

    #pragma unroll 8
    for (int kk = 0; kk < SEGLEN; ++kk) {
        const int k = kbase + kk;
        const float4 w0 = s_w0[k];      // wave-uniform -> ds_read broadcast
        const float4 w1 = s_w1[k];
        const float cx = w0.x, cy = w0.y, cz = w0.z, dtv = w0.w;
        const float mx = w1.x, my = w1.y, mz = w1.z, dk = w1.w;

        const float rx = px - cx, ry = py - cy;                // rz = -cz
        const float r2 = fmaf(rx, rx, fmaf(ry, ry, cz * cz));  // >= cz^2
        const float mdotr = fmaf(mz, -cz, fmaf(my, ry, mx * rx));
        const float t3 = 3.0f * mdotr;
        const float gx = fmaf(t3, rx, -(mx * r2));
        const float gy = fmaf(t3, ry, -(my * r2));
        const float gz = fmaf(t3, -cz, -(mz * r2));
        const float bxy2g = fmaf(gy, gy, gx * gx);
        const float b2g = fmaf(gz, gz, bxy2g);

        const float pr = __builtin_amdgcn_rcpf(r2);  // only transcendental
        const float p2 = pr * pr;
        const float S = p2 * p2 * pr;                // r^-10

        peak2 = fmaxf(peak2, (bxy2g * S) * dk);      // exact channel

        const float ux = fmaf(gpy, gz, -(gpz * gy));
        const float uy = fmaf(gpz, gx, -(gpx * gz));
        const float uz = fmaf(gpx, gy, -(gpy * gx));
        const float X2 = fmaf(uz, uz, fmaf(uy, uy, ux * ux));

        const bool active = X2 * S > 1e-10f * b2p;
        const bool use_rot = active && (X2 > 1e-12f * (b2g * b2p));

        gsx = use_rot ? gx : gsx;
        gsy = use_rot ? gy : gsy;
        gsz = use_rot ? gz : gsz;
        b2s = use_rot ? b2g : b2s;
        fired = use_rot ? 1.0f : fired;
        at += active ? dtv : 0.0f;

        gpx = gx; gpy = gy; gpz = gz; b2p = b2g;  // renames only
    }

    const float inv = __builtin_amdgcn_rsqf(b2s);
    sh_a[seg][pt] = make_float4(gsx * inv, gsy * inv, gsz * inv, at);
    sh_b[seg][pt] = make_float2(peak2, fired);
    __syncthreads();

    if (t < PTS) {
        float pk2 = 0.0f, atot = 0.0f;
        float fox = 0.0f, foy = 0.0f, foz = 1.0f;
        #pragma unroll
        for (int s = 0; s < NSEG; ++s) {
            const float4 a4 = sh_a[s][t];
            const float2 b2v = sh_b[s][t];
            pk2 = fmaxf(pk2, b2v.x);
            atot += a4.w;
            const bool f = b2v.y != 0.0f;
            fox = f ? a4.x : fox;
            foy = f ? a4.y : foy;
            foz = f ? a4.z : foz;
        }
        if (valid) {
            out[5 * p + 0] = fox;
            out[5 * p + 1] = foy;
            out[5 * p + 2] = foz;
            out[5 * p + 3] = atot;
            out[5 * p + 4] = sqrtf(pk2);
        }
    }
}

extern "C" void kernel_launch(void* const* d_in, const int* in_sizes, int n_in,
                              void* d_out, int out_size, void* d_ws, size_t ws_size,
                              hipStream_t stream) {
    const float* points = (const float*)d_in[0];
    const float* centers = (const float*)d_in[1];
    const float* raw_moment = (const float*)d_in[2];
    const float* raw_dwell = (const float*)d_in[3];
    float* out = (float*)d_out;
    (void)d_ws; (void)ws_size;

    const int n_points = in_sizes[0] / 3;

    const int grid = (n_points + PTS - 1) / PTS;
    // 4x identical idempotent launches: (bench - bench_r17)/3 = overhead+warm
    magnet_scan_r18<<<grid, BLOCK, 0, stream>>>(points, centers, raw_moment,
                                                raw_dwell, out, n_points);
    magnet_scan_r18<<<grid, BLOCK, 0, stream>>>(points, centers, raw_moment,
                                                raw_dwell, out, n_points);
    magnet_scan_r18<<<grid, BLOCK, 0, stream>>>(points, centers, raw_moment,
                                                raw_dwell, out, n_points);
    magnet_scan_r18<<<grid, BLOCK, 0, stream>>>(points, centers, raw_moment,
                                                raw_dwell, out, n_points);
}

// Round 19
// 68.682 us; speedup vs baseline: 1.4716x; 1.4716x over previous
//
#include <hip/hip_runtime.h>
#include <cmath>

#define NWP 128
#define NSEG 4
#define SEGLEN 32          // NWP / NSEG
#define PTS 64             // points per block
#define BLOCK 256          // PTS * NSEG = 4 waves

// r19 == r17 (best: 69.4 us), restored after the r18 4x-launch measurement
// probe. Final decomposition (r18): bench 69.4 = 40.3 harness d_ws fill
// + ~3 misc + ~10.6 dispatch+warm-exec + ~15.5 cold (L2 flush + clock ramp
// caused by the preceding 268 MB fill). Warm exec matches the issue model
// (~5-6 us); everything larger is harness-owned.
// Kernel: single-dispatch, exact-segmented, chain-free scan:
//   g = 3(m.r)r - m*r^2 (f = g/r^5), S = r^-10
//   peak2 = max_k(bxy2g_k*S_k*d_k), d_k = exp(-0.2*(127-k))  [exact channel]
//   active:  X2*S > 1e-10*b2p       (== bmag*sin > 1e-5)
//   use_rot: active && X2 > 1e-12*b2g*b2p  (== ... && sin > 1e-6)
//   orient = last fired bhat (snap: exp(-100*bmag*dt) ~ 0 for bmag >= ~20)
__global__ __launch_bounds__(BLOCK) void magnet_scan_r19(
    const float* __restrict__ points,
    const float* __restrict__ centers,
    const float* __restrict__ raw_moment,
    const float* __restrict__ raw_dwell,
    float* __restrict__ out,
    int n_points)
{
    __shared__ float4 s_w0[NWP];        // {cx, cy, cz, dt}
    __shared__ float4 s_w1[NWP];        // {mx, my, mz, d_k}
    __shared__ float4 sh_a[NSEG][PTS];  // {ox, oy, oz, at}
    __shared__ float2 sh_b[NSEG][PTS];  // {peak2, fired}

    const int t = threadIdx.x;
    if (t < NWP) {
        const float cx = centers[3 * t + 0];
        const float cy = centers[3 * t + 1];
        const float cz = centers[3 * t + 2];
        // tanh(x) = 1 - 2/(exp2(2x/ln2)+1)
        const float L2E2 = 2.8853900817779268f;  // 2/ln2
        const float ex0 = __builtin_amdgcn_exp2f(raw_moment[3 * t + 0] * L2E2);
        const float ex1 = __builtin_amdgcn_exp2f(raw_moment[3 * t + 1] * L2E2);
        const float ex2 = __builtin_amdgcn_exp2f(raw_moment[3 * t + 2] * L2E2);
        const float mx = 0.05f * (1.0f - 2.0f * __builtin_amdgcn_rcpf(ex0 + 1.0f));
        const float my = 0.05f * (1.0f - 2.0f * __builtin_amdgcn_rcpf(ex1 + 1.0f));
        const float mz = 0.05f * (1.0f - 2.0f * __builtin_amdgcn_rcpf(ex2 + 1.0f));
        // sigmoid(x) = 1/(1+exp2(-x/ln2))
        const float ed = __builtin_amdgcn_exp2f(raw_dwell[t] * -1.4426950408889634f);
        const float dtv = 0.01f + 0.19f * __builtin_amdgcn_rcpf(1.0f + ed);
        // d_k = exp2(-(0.2/ln2)*(127-k))
        const float dk = __builtin_amdgcn_exp2f(
            -0.28853900817779268f * (float)(NWP - 1 - t));
        s_w0[t] = make_float4(cx, cy, cz, dtv);
        s_w1[t] = make_float4(mx, my, mz, dk);
    }
    __syncthreads();

    const int pt = t & (PTS - 1);
    const int seg = t >> 6;             // == wave id
    int p = blockIdx.x * PTS + pt;
    const bool valid = p < n_points;
    p = valid ? p : (n_points - 1);

    const float px = points[3 * p + 0];
    const float py = points[3 * p + 1];
    // pz == 0 by construction (setup concatenates a zero z-column)

    const int kbase = seg * SEGLEN;

    // segment seed: field at kbase-1; segment 0 seeds with o0 = (0,0,1).
    float gpx = 0.0f, gpy = 0.0f, gpz = 1.0f, b2p = 1.0f;
    if (seg != 0) {
        const float4 w0 = s_w0[kbase - 1];
        const float4 w1 = s_w1[kbase - 1];
        const float rx = px - w0.x, ry = py - w0.y;
        const float r2 = fmaf(rx, rx, fmaf(ry, ry, w0.z * w0.z));
        const float mdotr = fmaf(w1.z, -w0.z, fmaf(w1.y, ry, w1.x * rx));
        const float t3 = 3.0f * mdotr;
        gpx = fmaf(t3, rx, -(w1.x * r2));
        gpy = fmaf(t3, ry, -(w1.y * r2));
        gpz = fmaf(t3, -w0.z, -(w1.z * r2));
        b2p = fmaf(gpz, gpz, fmaf(gpy, gpy, gpx * gpx));
    }

    float gsx = 0.0f, gsy = 0.0f, gsz = 1.0f, b2s = 1.0f;  // last fired
    float at = 0.0f, peak2 = 0.0f, fired = 0.0f;

    #pragma unroll 8
    for (int kk = 0; kk < SEGLEN; ++kk) {
        const int k = kbase + kk;
        const float4 w0 = s_w0[k];      // wave-uniform -> ds_read broadcast
        const float4 w1 = s_w1[k];
        const float cx = w0.x, cy = w0.y, cz = w0.z, dtv = w0.w;
        const float mx = w1.x, my = w1.y, mz = w1.z, dk = w1.w;

        const float rx = px - cx, ry = py - cy;                // rz = -cz
        const float r2 = fmaf(rx, rx, fmaf(ry, ry, cz * cz));  // >= cz^2
        const float mdotr = fmaf(mz, -cz, fmaf(my, ry, mx * rx));
        const float t3 = 3.0f * mdotr;
        const float gx = fmaf(t3, rx, -(mx * r2));
        const float gy = fmaf(t3, ry, -(my * r2));
        const float gz = fmaf(t3, -cz, -(mz * r2));
        const float bxy2g = fmaf(gy, gy, gx * gx);
        const float b2g = fmaf(gz, gz, bxy2g);

        const float pr = __builtin_amdgcn_rcpf(r2);  // only transcendental
        const float p2 = pr * pr;
        const float S = p2 * p2 * pr;                // r^-10

        peak2 = fmaxf(peak2, (bxy2g * S) * dk);      // exact channel

        const float ux = fmaf(gpy, gz, -(gpz * gy));
        const float uy = fmaf(gpz, gx, -(gpx * gz));
        const float uz = fmaf(gpx, gy, -(gpy * gx));
        const float X2 = fmaf(uz, uz, fmaf(uy, uy, ux * ux));

        const bool active = X2 * S > 1e-10f * b2p;
        const bool use_rot = active && (X2 > 1e-12f * (b2g * b2p));

        gsx = use_rot ? gx : gsx;
        gsy = use_rot ? gy : gsy;
        gsz = use_rot ? gz : gsz;
        b2s = use_rot ? b2g : b2s;
        fired = use_rot ? 1.0f : fired;
        at += active ? dtv : 0.0f;

        gpx = gx; gpy = gy; gpz = gz; b2p = b2g;  // renames only
    }

    const float inv = __builtin_amdgcn_rsqf(b2s);
    sh_a[seg][pt] = make_float4(gsx * inv, gsy * inv, gsz * inv, at);
    sh_b[seg][pt] = make_float2(peak2, fired);
    __syncthreads();

    if (t < PTS) {
        float pk2 = 0.0f, atot = 0.0f;
        float fox = 0.0f, foy = 0.0f, foz = 1.0f;
        #pragma unroll
        for (int s = 0; s < NSEG; ++s) {
            const float4 a4 = sh_a[s][t];
            const float2 b2v = sh_b[s][t];
            pk2 = fmaxf(pk2, b2v.x);   // global decay baked in -> plain max
            atot += a4.w;
            const bool f = b2v.y != 0.0f;
            fox = f ? a4.x : fox;
            foy = f ? a4.y : foy;
            foz = f ? a4.z : foz;
        }
        if (valid) {
            out[5 * p + 0] = fox;
            out[5 * p + 1] = foy;
            out[5 * p + 2] = foz;
            out[5 * p + 3] = atot;
            out[5 * p + 4] = sqrtf(pk2);
        }
    }
}

extern "C" void kernel_launch(void* const* d_in, const int* in_sizes, int n_in,
                              void* d_out, int out_size, void* d_ws, size_t ws_size,
                              hipStream_t stream) {
    const float* points = (const float*)d_in[0];
    const float* centers = (const float*)d_in[1];
    const float* raw_moment = (const float*)d_in[2];
    const float* raw_dwell = (const float*)d_in[3];
    float* out = (float*)d_out;
    (void)d_ws; (void)ws_size;  // single dispatch, no workspace

    const int n_points = in_sizes[0] / 3;

    const int grid = (n_points + PTS - 1) / PTS;
    magnet_scan_r19<<<grid, BLOCK, 0, stream>>>(points, centers, raw_moment,
                                                raw_dwell, out, n_points);
}